// Round 1
// baseline (88.707 us; speedup 1.0000x reference)
//
#include <hip/hip_runtime.h>

// upfirdn2d specialized: up=2, down=1, pad0=2, pad1=1 (eff trailing pad 2),
// 4x4 kernel, input (1024, 128, 128) f32 -> output (1024, 256, 256) f32.
//
// Polyphase decomposition: output (2r+py, 2c+px) uses
//   py=0: input rows r-1 (ky=0), r (ky=2); py=1: rows r (ky=1), r+1 (ky=3)
// and the same pattern in x. w[ky][kx] = kernel[3-ky][3-kx] (true conv flip).

__global__ __launch_bounds__(256) void upfirdn2d_up2_kernel(
    const float* __restrict__ x, const float* __restrict__ kern,
    float* __restrict__ out) {
  constexpr int H = 128, W = 128, OW = 256;

  const int tid = threadIdx.x;
  const int qc  = tid & 127;                         // quad col 0..127
  const int qr  = ((blockIdx.x & 63) << 1) | (tid >> 7);  // quad row 0..127
  const int img = blockIdx.x >> 6;                   // 0..1023

  // Flipped 4x4 kernel weights (uniform -> scalar loads).
  const float w00 = kern[15], w01 = kern[14], w02 = kern[13], w03 = kern[12];
  const float w10 = kern[11], w11 = kern[10], w12 = kern[9],  w13 = kern[8];
  const float w20 = kern[7],  w21 = kern[6],  w22 = kern[5],  w23 = kern[4];
  const float w30 = kern[3],  w31 = kern[2],  w32 = kern[1],  w33 = kern[0];

  const float* xi = x + (size_t)img * H * W;
  const int r = qr, c = qc;
  const bool cm = (c > 0), cp = (c < W - 1);

  float xm1m1 = 0.f, xm10 = 0.f, xm1p1 = 0.f;
  float x0m1  = 0.f, x00  = 0.f, x0p1  = 0.f;
  float xp1m1 = 0.f, xp10 = 0.f, xp1p1 = 0.f;

  if (r > 0) {
    const float* row = xi + (r - 1) * W;
    if (cm) xm1m1 = row[c - 1];
    xm10 = row[c];
    if (cp) xm1p1 = row[c + 1];
  }
  {
    const float* row = xi + r * W;
    if (cm) x0m1 = row[c - 1];
    x00 = row[c];
    if (cp) x0p1 = row[c + 1];
  }
  if (r < H - 1) {
    const float* row = xi + (r + 1) * W;
    if (cm) xp1m1 = row[c - 1];
    xp10 = row[c];
    if (cp) xp1p1 = row[c + 1];
  }

  // 2x2 output quad at (2r, 2c).
  const float o00 = w00 * xm1m1 + w02 * xm10 + w20 * x0m1 + w22 * x00;
  const float o01 = w01 * xm10 + w03 * xm1p1 + w21 * x00 + w23 * x0p1;
  const float o10 = w10 * x0m1 + w12 * x00 + w30 * xp1m1 + w32 * xp10;
  const float o11 = w11 * x00 + w13 * x0p1 + w31 * xp10 + w33 * xp1p1;

  float* orow0 = out + (size_t)img * OW * OW + (size_t)(2 * r) * OW + 2 * c;
  float* orow1 = orow0 + OW;
  *reinterpret_cast<float2*>(orow0) = make_float2(o00, o01);
  *reinterpret_cast<float2*>(orow1) = make_float2(o10, o11);
}

extern "C" void kernel_launch(void* const* d_in, const int* in_sizes, int n_in,
                              void* d_out, int out_size, void* d_ws, size_t ws_size,
                              hipStream_t stream) {
  const float* x    = (const float*)d_in[0];
  const float* kern = (const float*)d_in[1];
  float* out        = (float*)d_out;
  // 1024 images, each: 64 blocks x 256 threads (2 quad-rows of 128 quads).
  upfirdn2d_up2_kernel<<<dim3(1024 * 64), dim3(256), 0, stream>>>(x, kern, out);
}

// Round 3
// 62.119 us; speedup vs baseline: 1.4280x; 1.4280x over previous
//
#include <hip/hip_runtime.h>

// upfirdn2d specialized: up=2, down=1, pad0=2, eff trailing pad 2,
// 4x4 kernel, input (1024, 128, 128) f32 -> output (1024, 256, 256) f32.
//
// Polyphase: output (2r+py, 2c+px) mixes input rows {r-1,r} (py=0) or
// {r,r+1} (py=1), same in x. w[ky][kx] = kernel[3-ky][3-kx] (conv flip).
//
// Each thread: 4 input cols (one float4/row + 2 halo scalars, 3 rows)
// -> 2x8 output patch, stored as 4x float4 (16 B/lane, nontemporal).

typedef float f4 __attribute__((ext_vector_type(4)));

__global__ __launch_bounds__(256) void upfirdn2d_up2_kernel(
    const float* __restrict__ x, const float* __restrict__ kern,
    float* __restrict__ out) {
  constexpr int H = 128, W = 128, OW = 256;

  const int tid = threadIdx.x;
  const int c4  = tid & 31;                              // float4 col 0..31
  const int r   = ((blockIdx.x & 15) << 3) | (tid >> 5); // input row 0..127
  const int img = blockIdx.x >> 4;                       // 0..1023

  // Flipped 4x4 kernel weights (uniform -> scalar regs).
  const float w00 = kern[15], w01 = kern[14], w02 = kern[13], w03 = kern[12];
  const float w10 = kern[11], w11 = kern[10], w12 = kern[9],  w13 = kern[8];
  const float w20 = kern[7],  w21 = kern[6],  w22 = kern[5],  w23 = kern[4];
  const float w30 = kern[3],  w31 = kern[2],  w32 = kern[1],  w33 = kern[0];

  const float* xi = x + (size_t)img * H * W;
  const int x0 = c4 << 2;  // first input col of this thread

  // arr[0..5] = input cols x0-1 .. x0+4 (zero-padded at edges)
  float t[6], m[6], b[6];

  auto ldrow = [&](int rr, float* a) {
    if (rr >= 0 && rr < H) {
      const float* row = xi + rr * W + x0;
      const f4 v = *reinterpret_cast<const f4*>(row);
      a[0] = (c4 > 0)  ? row[-1] : 0.f;
      a[1] = v.x; a[2] = v.y; a[3] = v.z; a[4] = v.w;
      a[5] = (c4 < 31) ? row[4] : 0.f;
    } else {
      a[0] = a[1] = a[2] = a[3] = a[4] = a[5] = 0.f;
    }
  };
  ldrow(r - 1, t);
  ldrow(r,     m);
  ldrow(r + 1, b);

  float o0[8], o1[8];
#pragma unroll
  for (int j = 0; j < 4; ++j) {
    o0[2*j]   = w00 * t[j]   + w02 * t[j+1] + w20 * m[j]   + w22 * m[j+1];
    o0[2*j+1] = w01 * t[j+1] + w03 * t[j+2] + w21 * m[j+1] + w23 * m[j+2];
    o1[2*j]   = w10 * m[j]   + w12 * m[j+1] + w30 * b[j]   + w32 * b[j+1];
    o1[2*j+1] = w11 * m[j+1] + w13 * m[j+2] + w31 * b[j+1] + w33 * b[j+2];
  }

  float* orow0 = out + (size_t)img * OW * OW + (size_t)(2 * r) * OW + 2 * x0;
  float* orow1 = orow0 + OW;
  f4 v00 = {o0[0], o0[1], o0[2], o0[3]};
  f4 v01 = {o0[4], o0[5], o0[6], o0[7]};
  f4 v10 = {o1[0], o1[1], o1[2], o1[3]};
  f4 v11 = {o1[4], o1[5], o1[6], o1[7]};
  __builtin_nontemporal_store(v00, reinterpret_cast<f4*>(orow0));
  __builtin_nontemporal_store(v01, reinterpret_cast<f4*>(orow0 + 4));
  __builtin_nontemporal_store(v10, reinterpret_cast<f4*>(orow1));
  __builtin_nontemporal_store(v11, reinterpret_cast<f4*>(orow1 + 4));
}

extern "C" void kernel_launch(void* const* d_in, const int* in_sizes, int n_in,
                              void* d_out, int out_size, void* d_ws, size_t ws_size,
                              hipStream_t stream) {
  const float* x    = (const float*)d_in[0];
  const float* kern = (const float*)d_in[1];
  float* out        = (float*)d_out;
  // 1024 images x 16 blocks (8 input rows x 32 float4-cols per block).
  upfirdn2d_up2_kernel<<<dim3(1024 * 16), dim3(256), 0, stream>>>(x, kern, out);
}